// Round 17
// baseline (50.860 us; speedup 1.0000x reference)
//
#include <hip/hip_runtime.h>
#include <hip/hip_bf16.h>
#include <stdint.h>

// KANLayer: out[8192,512] = sum_{i,p} x^p+1 * (edge_w*comb_w) + bias  ==  A@W + bias.
// R17: Xpk DELETED. GEMM A-fragments load straight from x (f32): lane l, strip m reads
// x[bx*128+wr*64+m*16+(l&15)][g*32+(l>>4)*8 .. +7] as two float4 — the 64 lanes cover
// 16 rows x one full 128B line each (100% line utilization), L2-reused 8x per XCD via
// the bijective swizzle. Powers computed from f32 (cheaper VALU than bf16 unpack).
// Only Bpk (1.5MB, NT stores) + bias partials are pre-packed. Rolled ping-pong register
// pipeline, steady vmcnt(14), no LDS, no barriers.

static constexpr int ON_ = 512;

typedef __bf16 bf16x8 __attribute__((ext_vector_type(8)));
typedef float  f32x4  __attribute__((ext_vector_type(4)));

__device__ __forceinline__ unsigned int f2bf(float f) {
    unsigned int u = __float_as_uint(f);
    return ((u + 0x7FFFu + ((u >> 16) & 1u)) >> 16);   // RNE bf16, finite inputs
}

__device__ __forceinline__ void nt_store4(uint4* p, uint4 v) {
    __builtin_nontemporal_store(v.x, &p->x);
    __builtin_nontemporal_store(v.y, &p->y);
    __builtin_nontemporal_store(v.z, &p->z);
    __builtin_nontemporal_store(v.w, &p->w);
}

__device__ __forceinline__ float4 mul4(float4 a, float4 b) {
    return make_float4(a.x * b.x, a.y * b.y, a.z * b.z, a.w * b.w);
}

// ---- pack: blocks [0,128) B->Bpk ; [128,144) bias partials (8 x 512)
// Bpk chunk (cb, ks=g*3+p): lane l holds W[k][cb*16+(l&15)], k-in-chunk=(l>>4)*8+j.
__global__ __launch_bounds__(256) void pack_bw(const float* __restrict__ edge_w,
                                               const float* __restrict__ comb_w,
                                               const float* __restrict__ edge_b,
                                               uint4* __restrict__ Bpk,
                                               float* __restrict__ bias_part) {
    const int d = blockIdx.x;
    const int t = threadIdx.x;
    if (d < 128) {
        int id = d * 256 + t;
        int l  = id & 63;
        int u  = id >> 6;              // 0..511
        int g  = u & 15;
        int cb = u >> 4;               // 0..31
        int o  = cb * 16 + (l & 15);
        int i0 = g * 32 + ((l >> 4) << 3);
        unsigned int w[3][4];
#pragma unroll
        for (int j = 0; j < 4; ++j) {
            int ia = i0 + 2 * j, ic = ia + 1;
            float ca = comb_w[(size_t)ia * ON_ + o];
            float cc = comb_w[(size_t)ic * ON_ + o];
            const float* ea = edge_w + ((size_t)ia * ON_ + o) * 3;
            const float* ec = edge_w + ((size_t)ic * ON_ + o) * 3;
#pragma unroll
            for (int p = 0; p < 3; ++p)
                w[p][j] = f2bf(ea[p] * ca) | (f2bf(ec[p] * cc) << 16);
        }
        size_t base = ((size_t)cb * 48 + g * 3) * 64 + l;
        nt_store4(&Bpk[base],       make_uint4(w[0][0], w[0][1], w[0][2], w[0][3]));
        nt_store4(&Bpk[base + 64],  make_uint4(w[1][0], w[1][1], w[1][2], w[1][3]));
        nt_store4(&Bpk[base + 128], make_uint4(w[2][0], w[2][1], w[2][2], w[2][3]));
    } else {
        const int b  = d - 128;            // 0..15
        const int og = b >> 1, ih = b & 1;
        const int o  = og * 64 + (t & 63);
        const int s  = ih * 4 + (t >> 6);  // 0..7
        const int i0 = s * 64;
        float acc = 0.f;
#pragma unroll 8
        for (int i = i0; i < i0 + 64; ++i)
            acc += comb_w[(size_t)i * ON_ + o] * edge_b[(size_t)i * ON_ + o];
        __builtin_nontemporal_store(acc, &bias_part[s * ON_ + o]);
    }
}

#define CVT8F(LO, HI) \
    ((bf16x8){ (__bf16)(LO).x, (__bf16)(LO).y, (__bf16)(LO).z, (__bf16)(LO).w, \
               (__bf16)(HI).x, (__bf16)(HI).y, (__bf16)(HI).z, (__bf16)(HI).w })

// one 16-row strip from f32 pair (F0,F1): a^1,a^2,a^3 MFMAs into acc[MI][0..1]
#define STRIPF(MI, F0, F1, B0, B1, B2, B3, B4, B5) do {                                    \
    bf16x8 a1_ = CVT8F(F0, F1);                                                            \
    acc[MI][0] = __builtin_amdgcn_mfma_f32_16x16x32_bf16(a1_, __builtin_bit_cast(bf16x8, B0), acc[MI][0], 0, 0, 0); \
    acc[MI][1] = __builtin_amdgcn_mfma_f32_16x16x32_bf16(a1_, __builtin_bit_cast(bf16x8, B3), acc[MI][1], 0, 0, 0); \
    float4 q0_ = mul4(F0, F0), q1_ = mul4(F1, F1);                                         \
    bf16x8 a2_ = CVT8F(q0_, q1_);                                                          \
    acc[MI][0] = __builtin_amdgcn_mfma_f32_16x16x32_bf16(a2_, __builtin_bit_cast(bf16x8, B1), acc[MI][0], 0, 0, 0); \
    acc[MI][1] = __builtin_amdgcn_mfma_f32_16x16x32_bf16(a2_, __builtin_bit_cast(bf16x8, B4), acc[MI][1], 0, 0, 0); \
    float4 c0_ = mul4(q0_, F0), c1_ = mul4(q1_, F1);                                       \
    bf16x8 a3_ = CVT8F(c0_, c1_);                                                          \
    acc[MI][0] = __builtin_amdgcn_mfma_f32_16x16x32_bf16(a3_, __builtin_bit_cast(bf16x8, B2), acc[MI][0], 0, 0, 0); \
    acc[MI][1] = __builtin_amdgcn_mfma_f32_16x16x32_bf16(a3_, __builtin_bit_cast(bf16x8, B5), acc[MI][1], 0, 0, 0); \
} while (0)

#define COMP14(F0a, F0b, F1a, F1b, F2a, F2b, F3a, F3b, B0, B1, B2, B3, B4, B5) do {        \
    STRIPF(0, F0a, F0b, B0, B1, B2, B3, B4, B5);                                           \
    STRIPF(1, F1a, F1b, B0, B1, B2, B3, B4, B5);                                           \
    STRIPF(2, F2a, F2b, B0, B1, B2, B3, B4, B5);                                           \
    STRIPF(3, F3a, F3b, B0, B1, B2, B3, B4, B5);                                           \
} while (0)

// load group G (clamped; g=16 prefetch reads g=15 again — wasted but in-bounds)
// 8 x-gathers (full-line, L2-hot) + 6 B chunk loads = 14 VMEM
#define LOADG14(G, F0a, F0b, F1a, F1b, F2a, F2b, F3a, F3b, B0, B1, B2, B3, B4, B5) do {    \
    int gc_ = (G) < 16 ? (G) : 15;                                                         \
    const float* a0_ = pa0 + gc_ * 32;                                                     \
    const float* a1_ = pa1 + gc_ * 32;                                                     \
    const float* a2_ = pa2 + gc_ * 32;                                                     \
    const float* a3_ = pa3 + gc_ * 32;                                                     \
    F0a = *(const float4*)(a0_); F0b = *(const float4*)(a0_ + 4);                          \
    F1a = *(const float4*)(a1_); F1b = *(const float4*)(a1_ + 4);                          \
    F2a = *(const float4*)(a2_); F2b = *(const float4*)(a2_ + 4);                          \
    F3a = *(const float4*)(a3_); F3b = *(const float4*)(a3_ + 4);                          \
    const char* b0_ = pb0 + (size_t)gc_ * 3072;                                            \
    const char* b1_ = pb1 + (size_t)gc_ * 3072;                                            \
    B0 = *(const uint4*)(b0_);        B1 = *(const uint4*)(b0_ + 1024);                    \
    B2 = *(const uint4*)(b0_ + 2048); B3 = *(const uint4*)(b1_);                           \
    B4 = *(const uint4*)(b1_ + 1024); B5 = *(const uint4*)(b1_ + 2048);                    \
} while (0)

#define WAITV(N) asm volatile("s_waitcnt vmcnt(" #N ")" ::: "memory")

// GEMM: tile 128x64, 4 waves 2x2 (wr,wc), wave-tile 64x32. 512 blocks. No LDS/barriers.
__global__ __launch_bounds__(256, 2) void gemm_fused(const float* __restrict__ x,
                                                     const char* __restrict__ Bpk,
                                                     const float* __restrict__ bias_part,
                                                     float* __restrict__ out) {
    const int tid = threadIdx.x;
    const int l   = tid & 63;
    const int wid = tid >> 6;
    const int wr  = wid >> 1, wc = wid & 1;

    // bijective XCD swizzle (512 % 8 == 0): each XCD re-reads its 2MB x slice 8x (L2-hot)
    int d  = blockIdx.x;
    int w  = (d & 7) * 64 + (d >> 3);
    int bx = w >> 3, by = w & 7;

    // A sources: strip m, lane l -> row bx*128+wr*64+m*16+(l&15), col (l>>4)*8 (+g*32)
    const float* pa0 = x + (size_t)(bx * 128 + wr * 64 + (l & 15)) * 512 + ((l >> 4) << 3);
    const float* pa1 = pa0 + 16 * 512;
    const float* pa2 = pa0 + 32 * 512;
    const float* pa3 = pa0 + 48 * 512;
    const char*  pb0 = Bpk + ((size_t)(by * 4 + wc * 2) * 48) * 1024 + (l << 4);
    const char*  pb1 = pb0 + 48 * 1024;

    f32x4 acc[4][2] = {};
    float4 uF0a, uF0b, uF1a, uF1b, uF2a, uF2b, uF3a, uF3b;    // ping A (f32)
    uint4  uB0, uB1, uB2, uB3, uB4, uB5;                      // ping B
    float4 vF0a, vF0b, vF1a, vF1b, vF2a, vF2b, vF3a, vF3b;    // pong A
    uint4  vB0, vB1, vB2, vB3, vB4, vB5;                      // pong B

    LOADG14(0, uF0a, uF0b, uF1a, uF1b, uF2a, uF2b, uF3a, uF3b, uB0, uB1, uB2, uB3, uB4, uB5);

#pragma unroll 1
    for (int it = 0; it < 8; ++it) {   // computes groups 2*it, 2*it+1
        LOADG14(2 * it + 1, vF0a, vF0b, vF1a, vF1b, vF2a, vF2b, vF3a, vF3b, vB0, vB1, vB2, vB3, vB4, vB5);
        WAITV(14);
        COMP14(uF0a, uF0b, uF1a, uF1b, uF2a, uF2b, uF3a, uF3b, uB0, uB1, uB2, uB3, uB4, uB5);
        LOADG14(2 * it + 2, uF0a, uF0b, uF1a, uF1b, uF2a, uF2b, uF3a, uF3b, uB0, uB1, uB2, uB3, uB4, uB5);
        WAITV(14);
        COMP14(vF0a, vF0b, vF1a, vF1b, vF2a, vF2b, vF3a, vF3b, vB0, vB1, vB2, vB3, vB4, vB5);
    }

    // epilogue: C/D layout col=lane&15, row=(lane>>4)*4+reg; bias from 8 partials
    int lr = l >> 4, lc = l & 15;
#pragma unroll
    for (int n = 0; n < 2; ++n) {
        int o = (by << 6) + (wc << 5) + (n << 4) + lc;
        float bv = 0.f;
#pragma unroll
        for (int k = 0; k < 8; ++k) bv += bias_part[k * ON_ + o];
#pragma unroll
        for (int m = 0; m < 4; ++m) {
            int r0 = (bx << 7) + (wr << 6) + (m << 4) + (lr << 2);
#pragma unroll
            for (int j = 0; j < 4; ++j)
                out[(size_t)(r0 + j) * ON_ + o] = acc[m][n][j] + bv;
        }
    }
}

extern "C" void kernel_launch(void* const* d_in, const int* in_sizes, int n_in,
                              void* d_out, int out_size, void* d_ws, size_t ws_size,
                              hipStream_t stream) {
    const float* x      = (const float*)d_in[0];
    const float* edge_w = (const float*)d_in[1];
    const float* edge_b = (const float*)d_in[2];
    const float* comb_w = (const float*)d_in[3];
    float* out = (float*)d_out;

    char* ws = (char*)d_ws;
    char* Bpk        = ws;                     // 1536*512*2 = 1,572,864 B
    float* bias_part = (float*)(ws + 1572864); // 8*512*4    = 16,384 B

    hipLaunchKernelGGL(pack_bw, dim3(144), dim3(256), 0, stream,
                       edge_w, comb_w, edge_b, (uint4*)Bpk, bias_part);
    hipLaunchKernelGGL(gemm_fused, dim3(512), dim3(256), 0, stream, x, Bpk, bias_part, out);
}

// Round 18
// 36.651 us; speedup vs baseline: 1.3877x; 1.3877x over previous
//
#include <hip/hip_runtime.h>
#include <hip/hip_bf16.h>
#include <stdint.h>

// KANLayer as GEMM: out[8192,512] = A[8192,1536]@W[1536,512] + bias, bf16 MFMA, fp32 accum.
//   Xpk[rb][g]: 1KB chunk, lane l = bf16 x[rb*16+(l&15)][g*32+(l>>4)*8..+7]   (8 MB)
//   Bpk[cb][g][p]: 1KB chunk, lane l = bf16 W[k][cb*16+(l&15)]                (1.5 MB)
// R18 = R16 pack (best known) + gemm grid DOUBLED for cold-phase miss parallelism:
// BM=64, BN=64, 1024 blocks = 4 blocks/CU (grid was the occupancy limiter, 15%),
// wave-tile 32x32, 8 chunk loads/group, rolled ping-pong, steady vmcnt(8).
// XCD alignment @1024: gemm d reads rb in [4bx,4bx+4); those rb's pack blocks all have
// XCD rb>>6 = bx>>4 = (w>>7) = d&7 ✓ (producer XCD == consumer XCD preserved).

static constexpr int ON_ = 512;

typedef __bf16 bf16x8 __attribute__((ext_vector_type(8)));
typedef float  f32x4  __attribute__((ext_vector_type(4)));

__device__ __forceinline__ unsigned int f2bf(float f) {
    unsigned int u = __float_as_uint(f);
    return ((u + 0x7FFFu + ((u >> 16) & 1u)) >> 16);   // RNE bf16, finite inputs
}

__device__ __forceinline__ void nt_store4(uint4* p, uint4 v) {
    __builtin_nontemporal_store(v.x, &p->x);
    __builtin_nontemporal_store(v.y, &p->y);
    __builtin_nontemporal_store(v.z, &p->z);
    __builtin_nontemporal_store(v.w, &p->w);
}

// ---- pack: blocks [0,512) x->Xpk via LDS ; [512,640) B->Bpk ; [640,656) bias partials
__global__ __launch_bounds__(256) void pack_all(const float* __restrict__ x,
                                                const float* __restrict__ edge_w,
                                                const float* __restrict__ comb_w,
                                                const float* __restrict__ edge_b,
                                                uint4* __restrict__ Xpk,
                                                uint4* __restrict__ Bpk,
                                                float* __restrict__ bias_part) {
    __shared__ float xs[16 * 516];     // 16 rows, pitch 516 f32 -> even LDS banks
    const int d = blockIdx.x;
    const int t = threadIdx.x;
    if (d < 512) {
        const int rb = (d & 7) * 64 + (d >> 3);   // pack rb on XCD rb>>6
        const float* xb = x + (size_t)rb * 16 * 512;
#pragma unroll
        for (int it = 0; it < 8; ++it) {
            int e   = it * 1024 + t * 4;
            int row = e >> 9, col = e & 511;
            *(float4*)(xs + row * 516 + col) = *(const float4*)(xb + e);
        }
        __syncthreads();
        const int l = t & 63, wv = t >> 6;
        const float* src0 = xs + (l & 15) * 516 + ((l >> 4) << 3);
#pragma unroll
        for (int s = 0; s < 4; ++s) {
            const int g = wv * 4 + s;
            const float* src = src0 + g * 32;
            float4 v0 = *(const float4*)(src);
            float4 v1 = *(const float4*)(src + 4);
            uint4 o;
            o.x = f2bf(v0.x) | (f2bf(v0.y) << 16);
            o.y = f2bf(v0.z) | (f2bf(v0.w) << 16);
            o.z = f2bf(v1.x) | (f2bf(v1.y) << 16);
            o.w = f2bf(v1.z) | (f2bf(v1.w) << 16);
            Xpk[((size_t)rb * 16 + g) * 64 + l] = o;   // cached (local-XCD L2)
        }
    } else if (d < 640) {
        int id = (d - 512) * 256 + t;
        int l  = id & 63;
        int u  = id >> 6;              // 0..511
        int g  = u & 15;
        int cb = u >> 4;               // 0..31
        int o  = cb * 16 + (l & 15);
        int i0 = g * 32 + ((l >> 4) << 3);
        unsigned int w[3][4];
#pragma unroll
        for (int j = 0; j < 4; ++j) {
            int ia = i0 + 2 * j, ic = ia + 1;
            float ca = comb_w[(size_t)ia * ON_ + o];
            float cc = comb_w[(size_t)ic * ON_ + o];
            const float* ea = edge_w + ((size_t)ia * ON_ + o) * 3;
            const float* ec = edge_w + ((size_t)ic * ON_ + o) * 3;
#pragma unroll
            for (int p = 0; p < 3; ++p)
                w[p][j] = f2bf(ea[p] * ca) | (f2bf(ec[p] * cc) << 16);
        }
        size_t base = ((size_t)cb * 48 + g * 3) * 64 + l;
        nt_store4(&Bpk[base],       make_uint4(w[0][0], w[0][1], w[0][2], w[0][3]));
        nt_store4(&Bpk[base + 64],  make_uint4(w[1][0], w[1][1], w[1][2], w[1][3]));
        nt_store4(&Bpk[base + 128], make_uint4(w[2][0], w[2][1], w[2][2], w[2][3]));
    } else {
        const int b  = d - 640;            // 0..15
        const int og = b >> 1, ih = b & 1;
        const int o  = og * 64 + (t & 63);
        const int s  = ih * 4 + (t >> 6);  // 0..7
        const int i0 = s * 64;
        float acc = 0.f;
#pragma unroll 8
        for (int i = i0; i < i0 + 64; ++i)
            acc += comb_w[(size_t)i * ON_ + o] * edge_b[(size_t)i * ON_ + o];
        __builtin_nontemporal_store(acc, &bias_part[s * ON_ + o]);
    }
}

// one 16-row strip: a^1,a^2,a^3 MFMAs into acc[MI][0..1]
#define STRIP(Am, MI, BP0, BP1, BP2, BQ0, BQ1, BQ2) do {                                   \
    bf16x8 a1_ = __builtin_bit_cast(bf16x8, Am);                                           \
    acc[MI][0] = __builtin_amdgcn_mfma_f32_16x16x32_bf16(a1_, __builtin_bit_cast(bf16x8, BP0), acc[MI][0], 0, 0, 0); \
    acc[MI][1] = __builtin_amdgcn_mfma_f32_16x16x32_bf16(a1_, __builtin_bit_cast(bf16x8, BQ0), acc[MI][1], 0, 0, 0); \
    float e0_ = __uint_as_float((Am).x << 16), e1_ = __uint_as_float((Am).x & 0xffff0000u); \
    float e2_ = __uint_as_float((Am).y << 16), e3_ = __uint_as_float((Am).y & 0xffff0000u); \
    float e4_ = __uint_as_float((Am).z << 16), e5_ = __uint_as_float((Am).z & 0xffff0000u); \
    float e6_ = __uint_as_float((Am).w << 16), e7_ = __uint_as_float((Am).w & 0xffff0000u); \
    float q0_ = e0_*e0_, q1_ = e1_*e1_, q2_ = e2_*e2_, q3_ = e3_*e3_;                      \
    float q4_ = e4_*e4_, q5_ = e5_*e5_, q6_ = e6_*e6_, q7_ = e7_*e7_;                      \
    bf16x8 s_ = (bf16x8){ (__bf16)q0_, (__bf16)q1_, (__bf16)q2_, (__bf16)q3_,              \
                          (__bf16)q4_, (__bf16)q5_, (__bf16)q6_, (__bf16)q7_ };            \
    acc[MI][0] = __builtin_amdgcn_mfma_f32_16x16x32_bf16(s_, __builtin_bit_cast(bf16x8, BP1), acc[MI][0], 0, 0, 0); \
    acc[MI][1] = __builtin_amdgcn_mfma_f32_16x16x32_bf16(s_, __builtin_bit_cast(bf16x8, BQ1), acc[MI][1], 0, 0, 0); \
    bf16x8 c_ = (bf16x8){ (__bf16)(q0_*e0_), (__bf16)(q1_*e1_), (__bf16)(q2_*e2_), (__bf16)(q3_*e3_), \
                          (__bf16)(q4_*e4_), (__bf16)(q5_*e5_), (__bf16)(q6_*e6_), (__bf16)(q7_*e7_) }; \
    acc[MI][0] = __builtin_amdgcn_mfma_f32_16x16x32_bf16(c_, __builtin_bit_cast(bf16x8, BP2), acc[MI][0], 0, 0, 0); \
    acc[MI][1] = __builtin_amdgcn_mfma_f32_16x16x32_bf16(c_, __builtin_bit_cast(bf16x8, BQ2), acc[MI][1], 0, 0, 0); \
} while (0)

#define COMP8(A0, A1, B0, B1, B2, B3, B4, B5) do {                                         \
    STRIP(A0, 0, B0, B1, B2, B3, B4, B5);                                                  \
    STRIP(A1, 1, B0, B1, B2, B3, B4, B5);                                                  \
} while (0)

#define LOADG8(A0, A1, B0, B1, B2, B3, B4, B5) do {                                        \
    A0 = *(const uint4*)(pa0); A1 = *(const uint4*)(pa1);                                  \
    B0 = *(const uint4*)(pb0);        B1 = *(const uint4*)(pb0 + 1024);                    \
    B2 = *(const uint4*)(pb0 + 2048); B3 = *(const uint4*)(pb1);                           \
    B4 = *(const uint4*)(pb1 + 1024); B5 = *(const uint4*)(pb1 + 2048);                    \
    pa0 += 1024; pa1 += 1024; pb0 += 3072; pb1 += 3072;                                    \
} while (0)

#define WAITV(N) asm volatile("s_waitcnt vmcnt(" #N ")" ::: "memory")

// GEMM: tile 64x64, 4 waves 2x2 (wr,wc), wave-tile 32x32. 1024 blocks = 4/CU. No LDS.
__global__ __launch_bounds__(256, 4) void gemm_fused(const char* __restrict__ Xpk,
                                                     const char* __restrict__ Bpk,
                                                     const float* __restrict__ bias_part,
                                                     float* __restrict__ out) {
    const int tid = threadIdx.x;
    const int l   = tid & 63;
    const int wid = tid >> 6;
    const int wr  = wid >> 1, wc = wid & 1;

    // bijective XCD swizzle (1024 % 8 == 0)
    int d  = blockIdx.x;
    int w  = (d & 7) * 128 + (d >> 3);
    int bx = w >> 3, by = w & 7;       // bx 0..127, by 0..7

    const char* pa0 = Xpk + ((size_t)(bx * 4 + wr * 2) * 16) * 1024 + (l << 4);
    const char* pa1 = pa0 + 16 * 1024;
    const char* pb0 = Bpk + ((size_t)(by * 4 + wc * 2) * 48) * 1024 + (l << 4);
    const char* pb1 = pb0 + 48 * 1024;

    f32x4 acc[2][2] = {};
    uint4 uA0, uA1, uB0, uB1, uB2, uB3, uB4, uB5;   // ping
    uint4 vA0, vA1, vB0, vB1, vB2, vB3, vB4, vB5;   // pong

    LOADG8(uA0, uA1, uB0, uB1, uB2, uB3, uB4, uB5);   // group 0

#pragma unroll 1
    for (int it = 0; it < 8; ++it) {   // computes groups 2*it, 2*it+1
        LOADG8(vA0, vA1, vB0, vB1, vB2, vB3, vB4, vB5);
        WAITV(8);
        COMP8(uA0, uA1, uB0, uB1, uB2, uB3, uB4, uB5);
        if (it < 7) {
            LOADG8(uA0, uA1, uB0, uB1, uB2, uB3, uB4, uB5);
            WAITV(8);
        } else {
            WAITV(0);
        }
        COMP8(vA0, vA1, vB0, vB1, vB2, vB3, vB4, vB5);
    }

    // epilogue: C/D layout col=lane&15, row=(lane>>4)*4+reg; bias from 8 partials
    int lr = l >> 4, lc = l & 15;
#pragma unroll
    for (int n = 0; n < 2; ++n) {
        int o = (by << 6) + (wc << 5) + (n << 4) + lc;
        float bv = 0.f;
#pragma unroll
        for (int k = 0; k < 8; ++k) bv += bias_part[k * ON_ + o];
#pragma unroll
        for (int m = 0; m < 2; ++m) {
            int r0 = (bx << 6) + (wr << 5) + (m << 4) + (lr << 2);
#pragma unroll
            for (int j = 0; j < 4; ++j)
                out[(size_t)(r0 + j) * ON_ + o] = acc[m][n][j] + bv;
        }
    }
}

extern "C" void kernel_launch(void* const* d_in, const int* in_sizes, int n_in,
                              void* d_out, int out_size, void* d_ws, size_t ws_size,
                              hipStream_t stream) {
    const float* x      = (const float*)d_in[0];
    const float* edge_w = (const float*)d_in[1];
    const float* edge_b = (const float*)d_in[2];
    const float* comb_w = (const float*)d_in[3];
    float* out = (float*)d_out;

    char* ws = (char*)d_ws;
    char* Xpk        = ws;                               // 8192*512*2   = 8,388,608 B
    char* Bpk        = ws + 8388608;                     // 1536*512*2   = 1,572,864 B
    float* bias_part = (float*)(ws + 8388608 + 1572864); // 8*512*4      = 16,384 B

    hipLaunchKernelGGL(pack_all, dim3(512 + 128 + 16), dim3(256), 0, stream,
                       x, edge_w, comb_w, edge_b, (uint4*)Xpk, (uint4*)Bpk, bias_part);
    hipLaunchKernelGGL(gemm_fused, dim3(1024), dim3(256), 0, stream, Xpk, Bpk, bias_part, out);
}

// Round 19
// 33.279 us; speedup vs baseline: 1.5283x; 1.1013x over previous
//
#include <hip/hip_runtime.h>
#include <hip/hip_bf16.h>
#include <stdint.h>

// KANLayer as GEMM: out[8192,512] = A[8192,1536]@W[1536,512] + bias, bf16 MFMA, fp32 accum.
//   Xpk[rb][g]: 1KB chunk, lane l = bf16 x[rb*16+(l&15)][g*32+(l>>4)*8..+7]   (8 MB)
//   Bpk[cb][g][p]: 1KB chunk, lane l = bf16 W[k][cb*16+(l&15)]                (1.5 MB)
// R19 = R16 pack + gemm with DEPTH-2 register prefetch (3 named sets U/V/W, 30 loads in
// flight, vmcnt(20)) to raise cold-phase HBM miss parallelism. A-loads issued before
// B-loads (A unique per block -> real misses; B shared -> L2/MSHR-merged).
// Outstanding-count proof: before COMP(set g): issued sets g,g+1,g+2 = 30; WAITV(20)
// drains set g. Tail: 20 (g12) / 20 (g13) / 10 (g14) / 0 (g15).

static constexpr int ON_ = 512;

typedef __bf16 bf16x8 __attribute__((ext_vector_type(8)));
typedef float  f32x4  __attribute__((ext_vector_type(4)));

__device__ __forceinline__ unsigned int f2bf(float f) {
    unsigned int u = __float_as_uint(f);
    return ((u + 0x7FFFu + ((u >> 16) & 1u)) >> 16);   // RNE bf16, finite inputs
}

__device__ __forceinline__ void nt_store4(uint4* p, uint4 v) {
    __builtin_nontemporal_store(v.x, &p->x);
    __builtin_nontemporal_store(v.y, &p->y);
    __builtin_nontemporal_store(v.z, &p->z);
    __builtin_nontemporal_store(v.w, &p->w);
}

// ---- pack: blocks [0,512) x->Xpk via LDS ; [512,640) B->Bpk ; [640,656) bias partials
__global__ __launch_bounds__(256) void pack_all(const float* __restrict__ x,
                                                const float* __restrict__ edge_w,
                                                const float* __restrict__ comb_w,
                                                const float* __restrict__ edge_b,
                                                uint4* __restrict__ Xpk,
                                                uint4* __restrict__ Bpk,
                                                float* __restrict__ bias_part) {
    __shared__ float xs[16 * 516];     // 16 rows, pitch 516 f32 -> even LDS banks
    const int d = blockIdx.x;
    const int t = threadIdx.x;
    if (d < 512) {
        const int rb = (d & 7) * 64 + (d >> 3);   // producer XCD == consumer XCD
        const float* xb = x + (size_t)rb * 16 * 512;
#pragma unroll
        for (int it = 0; it < 8; ++it) {
            int e   = it * 1024 + t * 4;
            int row = e >> 9, col = e & 511;
            *(float4*)(xs + row * 516 + col) = *(const float4*)(xb + e);
        }
        __syncthreads();
        const int l = t & 63, wv = t >> 6;
        const float* src0 = xs + (l & 15) * 516 + ((l >> 4) << 3);
#pragma unroll
        for (int s = 0; s < 4; ++s) {
            const int g = wv * 4 + s;
            const float* src = src0 + g * 32;
            float4 v0 = *(const float4*)(src);
            float4 v1 = *(const float4*)(src + 4);
            uint4 o;
            o.x = f2bf(v0.x) | (f2bf(v0.y) << 16);
            o.y = f2bf(v0.z) | (f2bf(v0.w) << 16);
            o.z = f2bf(v1.x) | (f2bf(v1.y) << 16);
            o.w = f2bf(v1.z) | (f2bf(v1.w) << 16);
            Xpk[((size_t)rb * 16 + g) * 64 + l] = o;   // cached (local-XCD L2)
        }
    } else if (d < 640) {
        int id = (d - 512) * 256 + t;
        int l  = id & 63;
        int u  = id >> 6;              // 0..511
        int g  = u & 15;
        int cb = u >> 4;               // 0..31
        int o  = cb * 16 + (l & 15);
        int i0 = g * 32 + ((l >> 4) << 3);
        unsigned int w[3][4];
#pragma unroll
        for (int j = 0; j < 4; ++j) {
            int ia = i0 + 2 * j, ic = ia + 1;
            float ca = comb_w[(size_t)ia * ON_ + o];
            float cc = comb_w[(size_t)ic * ON_ + o];
            const float* ea = edge_w + ((size_t)ia * ON_ + o) * 3;
            const float* ec = edge_w + ((size_t)ic * ON_ + o) * 3;
#pragma unroll
            for (int p = 0; p < 3; ++p)
                w[p][j] = f2bf(ea[p] * ca) | (f2bf(ec[p] * cc) << 16);
        }
        size_t base = ((size_t)cb * 48 + g * 3) * 64 + l;
        nt_store4(&Bpk[base],       make_uint4(w[0][0], w[0][1], w[0][2], w[0][3]));
        nt_store4(&Bpk[base + 64],  make_uint4(w[1][0], w[1][1], w[1][2], w[1][3]));
        nt_store4(&Bpk[base + 128], make_uint4(w[2][0], w[2][1], w[2][2], w[2][3]));
    } else {
        const int b  = d - 640;            // 0..15
        const int og = b >> 1, ih = b & 1;
        const int o  = og * 64 + (t & 63);
        const int s  = ih * 4 + (t >> 6);  // 0..7
        const int i0 = s * 64;
        float acc = 0.f;
#pragma unroll 8
        for (int i = i0; i < i0 + 64; ++i)
            acc += comb_w[(size_t)i * ON_ + o] * edge_b[(size_t)i * ON_ + o];
        __builtin_nontemporal_store(acc, &bias_part[s * ON_ + o]);
    }
}

// one 16-row strip: a^1,a^2,a^3 MFMAs into acc[MI][0..1]
#define STRIP(Am, MI, BP0, BP1, BP2, BQ0, BQ1, BQ2) do {                                   \
    bf16x8 a1_ = __builtin_bit_cast(bf16x8, Am);                                           \
    acc[MI][0] = __builtin_amdgcn_mfma_f32_16x16x32_bf16(a1_, __builtin_bit_cast(bf16x8, BP0), acc[MI][0], 0, 0, 0); \
    acc[MI][1] = __builtin_amdgcn_mfma_f32_16x16x32_bf16(a1_, __builtin_bit_cast(bf16x8, BQ0), acc[MI][1], 0, 0, 0); \
    float e0_ = __uint_as_float((Am).x << 16), e1_ = __uint_as_float((Am).x & 0xffff0000u); \
    float e2_ = __uint_as_float((Am).y << 16), e3_ = __uint_as_float((Am).y & 0xffff0000u); \
    float e4_ = __uint_as_float((Am).z << 16), e5_ = __uint_as_float((Am).z & 0xffff0000u); \
    float e6_ = __uint_as_float((Am).w << 16), e7_ = __uint_as_float((Am).w & 0xffff0000u); \
    float q0_ = e0_*e0_, q1_ = e1_*e1_, q2_ = e2_*e2_, q3_ = e3_*e3_;                      \
    float q4_ = e4_*e4_, q5_ = e5_*e5_, q6_ = e6_*e6_, q7_ = e7_*e7_;                      \
    bf16x8 s_ = (bf16x8){ (__bf16)q0_, (__bf16)q1_, (__bf16)q2_, (__bf16)q3_,              \
                          (__bf16)q4_, (__bf16)q5_, (__bf16)q6_, (__bf16)q7_ };            \
    acc[MI][0] = __builtin_amdgcn_mfma_f32_16x16x32_bf16(s_, __builtin_bit_cast(bf16x8, BP1), acc[MI][0], 0, 0, 0); \
    acc[MI][1] = __builtin_amdgcn_mfma_f32_16x16x32_bf16(s_, __builtin_bit_cast(bf16x8, BQ1), acc[MI][1], 0, 0, 0); \
    bf16x8 c_ = (bf16x8){ (__bf16)(q0_*e0_), (__bf16)(q1_*e1_), (__bf16)(q2_*e2_), (__bf16)(q3_*e3_), \
                          (__bf16)(q4_*e4_), (__bf16)(q5_*e5_), (__bf16)(q6_*e6_), (__bf16)(q7_*e7_) }; \
    acc[MI][0] = __builtin_amdgcn_mfma_f32_16x16x32_bf16(c_, __builtin_bit_cast(bf16x8, BP2), acc[MI][0], 0, 0, 0); \
    acc[MI][1] = __builtin_amdgcn_mfma_f32_16x16x32_bf16(c_, __builtin_bit_cast(bf16x8, BQ2), acc[MI][1], 0, 0, 0); \
} while (0)

#define COMP10(A0, A1, A2, A3, B0, B1, B2, B3, B4, B5) do {                                \
    STRIP(A0, 0, B0, B1, B2, B3, B4, B5);                                                  \
    STRIP(A1, 1, B0, B1, B2, B3, B4, B5);                                                  \
    STRIP(A2, 2, B0, B1, B2, B3, B4, B5);                                                  \
    STRIP(A3, 3, B0, B1, B2, B3, B4, B5);                                                  \
} while (0)

// A chunks first (unique -> real HBM misses get head start), then B (shared, L2-merged)
#define LOADG10(A0, A1, A2, A3, B0, B1, B2, B3, B4, B5) do {                               \
    A0 = *(const uint4*)(pa0); A1 = *(const uint4*)(pa1);                                  \
    A2 = *(const uint4*)(pa2); A3 = *(const uint4*)(pa3);                                  \
    B0 = *(const uint4*)(pb0);        B1 = *(const uint4*)(pb0 + 1024);                    \
    B2 = *(const uint4*)(pb0 + 2048); B3 = *(const uint4*)(pb1);                           \
    B4 = *(const uint4*)(pb1 + 1024); B5 = *(const uint4*)(pb1 + 2048);                    \
    pa0 += 1024; pa1 += 1024; pa2 += 1024; pa3 += 1024;                                    \
    pb0 += 3072; pb1 += 3072;                                                              \
} while (0)

#define WAITV(N) asm volatile("s_waitcnt vmcnt(" #N ")" ::: "memory")

// GEMM: tile 128x64, 4 waves 2x2 (wr,wc), wave-tile 64x32. 512 blocks. No LDS/barriers.
// Depth-2 prefetch: 3 named sets, 30 loads in flight, vmcnt(20) steady.
__global__ __launch_bounds__(256, 2) void gemm_fused(const char* __restrict__ Xpk,
                                                     const char* __restrict__ Bpk,
                                                     const float* __restrict__ bias_part,
                                                     float* __restrict__ out) {
    const int tid = threadIdx.x;
    const int l   = tid & 63;
    const int wid = tid >> 6;
    const int wr  = wid >> 1, wc = wid & 1;

    // bijective XCD swizzle (512 % 8 == 0)
    int d  = blockIdx.x;
    int w  = (d & 7) * 64 + (d >> 3);
    int bx = w >> 3, by = w & 7;

    const char* pa0 = Xpk + ((size_t)(bx * 8 + wr * 4) * 16) * 1024 + (l << 4);
    const char* pa1 = pa0 + 16 * 1024;
    const char* pa2 = pa0 + 32 * 1024;
    const char* pa3 = pa0 + 48 * 1024;
    const char* pb0 = Bpk + ((size_t)(by * 4 + wc * 2) * 48) * 1024 + (l << 4);
    const char* pb1 = pb0 + 48 * 1024;

    f32x4 acc[4][2] = {};
    uint4 uA0, uA1, uA2, uA3, uB0, uB1, uB2, uB3, uB4, uB5;   // set U
    uint4 vA0, vA1, vA2, vA3, vB0, vB1, vB2, vB3, vB4, vB5;   // set V
    uint4 wA0, wA1, wA2, wA3, wB0, wB1, wB2, wB3, wB4, wB5;   // set W

    // prologue: g0 -> U, g1 -> V (20 loads in flight)
    LOADG10(uA0, uA1, uA2, uA3, uB0, uB1, uB2, uB3, uB4, uB5);
    LOADG10(vA0, vA1, vA2, vA3, vB0, vB1, vB2, vB3, vB4, vB5);

#pragma unroll 1
    for (int tr = 0; tr < 4; ++tr) {   // computes g = 3tr, 3tr+1, 3tr+2 (g0..g11)
        LOADG10(wA0, wA1, wA2, wA3, wB0, wB1, wB2, wB3, wB4, wB5);   // g=3tr+2
        WAITV(20);
        COMP10(uA0, uA1, uA2, uA3, uB0, uB1, uB2, uB3, uB4, uB5);    // g=3tr
        LOADG10(uA0, uA1, uA2, uA3, uB0, uB1, uB2, uB3, uB4, uB5);   // g=3tr+3
        WAITV(20);
        COMP10(vA0, vA1, vA2, vA3, vB0, vB1, vB2, vB3, vB4, vB5);    // g=3tr+1
        LOADG10(vA0, vA1, vA2, vA3, vB0, vB1, vB2, vB3, vB4, vB5);   // g=3tr+4
        WAITV(20);
        COMP10(wA0, wA1, wA2, wA3, wB0, wB1, wB2, wB3, wB4, wB5);    // g=3tr+2
    }
    // after loop: loaded g0..g13 (14 LOADG); U=g12, V=g13 pending
    LOADG10(wA0, wA1, wA2, wA3, wB0, wB1, wB2, wB3, wB4, wB5);       // g14
    WAITV(20);
    COMP10(uA0, uA1, uA2, uA3, uB0, uB1, uB2, uB3, uB4, uB5);        // g12
    LOADG10(uA0, uA1, uA2, uA3, uB0, uB1, uB2, uB3, uB4, uB5);       // g15 (16th)
    WAITV(20);
    COMP10(vA0, vA1, vA2, vA3, vB0, vB1, vB2, vB3, vB4, vB5);        // g13
    WAITV(10);
    COMP10(wA0, wA1, wA2, wA3, wB0, wB1, wB2, wB3, wB4, wB5);        // g14
    WAITV(0);
    COMP10(uA0, uA1, uA2, uA3, uB0, uB1, uB2, uB3, uB4, uB5);        // g15

    // epilogue: C/D layout col=lane&15, row=(lane>>4)*4+reg; bias from 8 partials
    int lr = l >> 4, lc = l & 15;
#pragma unroll
    for (int n = 0; n < 2; ++n) {
        int o = (by << 6) + (wc << 5) + (n << 4) + lc;
        float bv = 0.f;
#pragma unroll
        for (int k = 0; k < 8; ++k) bv += bias_part[k * ON_ + o];
#pragma unroll
        for (int m = 0; m < 4; ++m) {
            int r0 = (bx << 7) + (wr << 6) + (m << 4) + (lr << 2);
#pragma unroll
            for (int j = 0; j < 4; ++j)
                out[(size_t)(r0 + j) * ON_ + o] = acc[m][n][j] + bv;
        }
    }
}

extern "C" void kernel_launch(void* const* d_in, const int* in_sizes, int n_in,
                              void* d_out, int out_size, void* d_ws, size_t ws_size,
                              hipStream_t stream) {
    const float* x      = (const float*)d_in[0];
    const float* edge_w = (const float*)d_in[1];
    const float* edge_b = (const float*)d_in[2];
    const float* comb_w = (const float*)d_in[3];
    float* out = (float*)d_out;

    char* ws = (char*)d_ws;
    char* Xpk        = ws;                               // 8192*512*2   = 8,388,608 B
    char* Bpk        = ws + 8388608;                     // 1536*512*2   = 1,572,864 B
    float* bias_part = (float*)(ws + 8388608 + 1572864); // 8*512*4      = 16,384 B

    hipLaunchKernelGGL(pack_all, dim3(512 + 128 + 16), dim3(256), 0, stream,
                       x, edge_w, comb_w, edge_b, (uint4*)Xpk, (uint4*)Bpk, bias_part);
    hipLaunchKernelGGL(gemm_fused, dim3(512), dim3(256), 0, stream, Xpk, Bpk, bias_part, out);
}